// Round 12
// baseline (1239.729 us; speedup 1.0000x reference)
//
#include <hip/hip_runtime.h>

#define NUM_USER 50000
#define NUM_ITEM 25000
#define N_NODES 75000
#define DIM 64
#define N_INTENTS 128
#define N_EDGES 800000

// ---------------- CSR build ----------------

__global__ __launch_bounds__(256) void zero_cnt_kernel(int* __restrict__ cnt, int n) {
  int i = blockIdx.x * 256 + threadIdx.x;
  if (i < n) cnt[i] = 0;
}

__global__ __launch_bounds__(256) void count_kernel(const int* __restrict__ h, const int* __restrict__ t,
                                                    int* __restrict__ cnt) {
  int e = blockIdx.x * 256 + threadIdx.x;
  if (e >= N_EDGES) return;
  atomicAdd(&cnt[h[e]], 1);
  atomicAdd(&cnt[t[e]], 1);
}

// Single-block exclusive scan over n=75000 counts; also emits cursor copy and dinv.
__global__ __launch_bounds__(1024) void scan_kernel(const int* __restrict__ cnt, int* __restrict__ off,
                                                    int* __restrict__ cursor, float* __restrict__ dinv, int n) {
  __shared__ int wsum[16];
  __shared__ int carry_s;
  int tid = threadIdx.x, lane = tid & 63, wid = tid >> 6;
  if (tid == 0) carry_s = 0;
  __syncthreads();
  for (int base = 0; base < n; base += 1024) {
    int idx = base + tid;
    int orig = (idx < n) ? cnt[idx] : 0;
    int v = orig;
#pragma unroll
    for (int d = 1; d < 64; d <<= 1) {
      int u = __shfl_up(v, d, 64);
      if (lane >= d) v += u;
    }
    if (lane == 63) wsum[wid] = v;
    __syncthreads();
    if (tid == 0) {
      int run = carry_s;
#pragma unroll
      for (int i = 0; i < 16; i++) { int tmp = wsum[i]; wsum[i] = run; run += tmp; }
      carry_s = run;
    }
    __syncthreads();
    if (idx < n) {
      int excl = wsum[wid] + v - orig;
      off[idx] = excl;
      cursor[idx] = excl;
      dinv[idx] = rsqrtf((float)orig + 1e-7f);
    }
    __syncthreads();
  }
  if (tid == 0) off[n] = carry_s;
}

__global__ __launch_bounds__(256) void fill_kernel(const int* __restrict__ h, const int* __restrict__ t,
                                                   int* __restrict__ cursor, int* __restrict__ colarr) {
  int e = blockIdx.x * 256 + threadIdx.x;
  if (e >= N_EDGES) return;
  int hv = h[e], tv = t[e];
  int p1 = atomicAdd(&cursor[hv], 1);
  colarr[p1] = tv;
  int p2 = atomicAdd(&cursor[tv], 1);
  colarr[p2] = hv;
}

__global__ __launch_bounds__(256) void xinit_kernel(float4* __restrict__ x, const float4* __restrict__ ue,
                                                    const float4* __restrict__ ie) {
  int i = blockIdx.x * 256 + threadIdx.x;
  if (i >= N_NODES * 16) return;
  x[i] = (i < NUM_USER * 16) ? ue[i] : ie[i - NUM_USER * 16];
}

// W [64][128] row-major  ->  WT [128][64] row-major (columns become contiguous 256B)
__global__ __launch_bounds__(256) void wtrans_kernel(const float* __restrict__ Wu, const float* __restrict__ Wi,
                                                     float* __restrict__ WTu, float* __restrict__ WTi) {
  int i = blockIdx.x * 256 + threadIdx.x;
  if (i >= DIM * N_INTENTS) return;
  int d = i >> 7, j = i & 127;
  WTu[j * 64 + d] = Wu[i];
  WTi[j * 64 + d] = Wi[i];
}

// ---------------- Per-layer kernels ----------------

// gnn[row] = dinv[row] * sum_c dinv[c] * x[c]; also invn_g[row] = 1/max(||gnn[row]||,1e-12)
__global__ __launch_bounds__(256) void spmm_kernel(const int* __restrict__ off, const int* __restrict__ colarr,
                                                   const float* __restrict__ dinv, const float* __restrict__ x,
                                                   float* __restrict__ gnn, float* __restrict__ invn) {
  int tid = threadIdx.x;
  int row = blockIdx.x * 16 + (tid >> 4);
  int sub = tid & 15;
  if (row >= N_NODES) return;
  int s = off[row], e = off[row + 1];
  const float4* x4 = (const float4*)x;
  float4 acc = make_float4(0.f, 0.f, 0.f, 0.f);
  for (int i = s; i < e; i++) {
    int c = colarr[i];
    float w = dinv[c];
    float4 xv = x4[c * 16 + sub];
    acc.x = fmaf(w, xv.x, acc.x);
    acc.y = fmaf(w, xv.y, acc.y);
    acc.z = fmaf(w, xv.z, acc.z);
    acc.w = fmaf(w, xv.w, acc.w);
  }
  float dr = dinv[row];
  acc.x *= dr; acc.y *= dr; acc.z *= dr; acc.w *= dr;
  ((float4*)gnn)[row * 16 + sub] = acc;
  float ss = acc.x * acc.x + acc.y * acc.y + acc.z * acc.z + acc.w * acc.w;
  ss += __shfl_xor(ss, 1); ss += __shfl_xor(ss, 2);
  ss += __shfl_xor(ss, 4); ss += __shfl_xor(ss, 8);
  if (sub == 0) invn[row] = 1.f / fmaxf(sqrtf(ss), 1e-12f);
}

// intl[row] = softmax(x[row] @ W) @ W^T.
// Round-5 structure (fixing grid-too-small: 294 blocks -> 1173):
//   64 rows/block, 256 threads.
//   Phase 1: wave w computes scores for j in [32w,32w+32), one row per lane,
//            row in 16 float4 VGPRs, W columns read from pre-transposed WT
//            (wave-uniform global loads, L1-resident 32KB). Cross-wave max/sum
//            via 1KB LDS; raw e_j stored to LDS Pe[r][j ^ (r&31)] (2-way max).
//   Phase 2: thread (r = tid>>2, dq = tid&3) computes o[dq*16..dq*16+16) =
//            sum_j e_j * WT[j][.] (Pe reads broadcast+conflict-free), scales
//            by 1/l, stores coalesced, row-norm partials combined via LDS.
__global__ __launch_bounds__(256) void intent_kernel(const float* __restrict__ x,
                                                     const float* __restrict__ WTu,
                                                     const float* __restrict__ WTi,
                                                     float* __restrict__ outl, float* __restrict__ invn) {
  __shared__ float Pe[64 * 128];   // 32 KB, swizzled columns
  __shared__ float pm[4][64];
  __shared__ float pl[4][64];
  __shared__ float pss[64][4];
  const int UT = (NUM_USER + 63) / 64;  // 782
  int b = blockIdx.x;
  const float* WT;
  int row0, rend;
  if (b < UT) { WT = WTu; row0 = b * 64; rend = NUM_USER; }
  else        { WT = WTi; row0 = NUM_USER + (b - UT) * 64; rend = N_NODES; }
  int tid = threadIdx.x, w = tid >> 6, lane = tid & 63;
  const float4* WT4 = (const float4*)WT;
  const float4* x4 = (const float4*)x;

  // ---- phase 1: scores for this wave's 32 intents ----
  int row = row0 + lane;
  bool act = row < rend;
  float4 zf4 = make_float4(0.f, 0.f, 0.f, 0.f);
  float4 xr[16];
#pragma unroll
  for (int q = 0; q < 16; q++) xr[q] = act ? x4[(size_t)row * 16 + q] : zf4;

  float s[32];
  int j0 = w * 32;
#pragma unroll
  for (int jj = 0; jj < 32; jj++) {
    const float4* wj = WT4 + (size_t)(j0 + jj) * 16;
    float s0 = 0.f, s1 = 0.f, s2 = 0.f, s3 = 0.f;
#pragma unroll
    for (int q = 0; q < 16; q += 4) {
      float4 a0 = xr[q], w0 = wj[q];
      float4 a1 = xr[q + 1], w1 = wj[q + 1];
      float4 a2 = xr[q + 2], w2 = wj[q + 2];
      float4 a3 = xr[q + 3], w3 = wj[q + 3];
      s0 = fmaf(a0.x, w0.x, s0); s0 = fmaf(a0.y, w0.y, s0); s0 = fmaf(a0.z, w0.z, s0); s0 = fmaf(a0.w, w0.w, s0);
      s1 = fmaf(a1.x, w1.x, s1); s1 = fmaf(a1.y, w1.y, s1); s1 = fmaf(a1.z, w1.z, s1); s1 = fmaf(a1.w, w1.w, s1);
      s2 = fmaf(a2.x, w2.x, s2); s2 = fmaf(a2.y, w2.y, s2); s2 = fmaf(a2.z, w2.z, s2); s2 = fmaf(a2.w, w2.w, s2);
      s3 = fmaf(a3.x, w3.x, s3); s3 = fmaf(a3.y, w3.y, s3); s3 = fmaf(a3.z, w3.z, s3); s3 = fmaf(a3.w, w3.w, s3);
    }
    s[jj] = (s0 + s1) + (s2 + s3);
  }
  float pmax = s[0];
#pragma unroll
  for (int jj = 1; jj < 32; jj++) pmax = fmaxf(pmax, s[jj]);
  pm[w][lane] = pmax;
  __syncthreads();
  float m = fmaxf(fmaxf(pm[0][lane], pm[1][lane]), fmaxf(pm[2][lane], pm[3][lane]));
  float psum = 0.f;
  int sw = lane & 31;
#pragma unroll
  for (int jj = 0; jj < 32; jj++) {
    float e = expf(s[jj] - m);
    psum += e;
    Pe[lane * 128 + ((j0 + jj) ^ sw)] = e;
  }
  pl[w][lane] = psum;
  __syncthreads();

  // ---- phase 2: projection, thread = (row r, dim-quad dq) ----
  int r = tid >> 2, dq = tid & 3;
  float lsum = (pl[0][r] + pl[1][r]) + (pl[2][r] + pl[3][r]);
  float invl = 1.f / lsum;  // >=1: max score contributes e=1
  int rsw = r & 31;
  float4 o0 = zf4, o1 = zf4, o2 = zf4, o3 = zf4;
#pragma unroll 4
  for (int j = 0; j < N_INTENTS; j++) {
    float e = Pe[r * 128 + (j ^ rsw)];
    const float4* wj = WT4 + (size_t)j * 16 + dq * 4;
    float4 w0 = wj[0], w1 = wj[1], w2 = wj[2], w3 = wj[3];
    o0.x = fmaf(e, w0.x, o0.x); o0.y = fmaf(e, w0.y, o0.y); o0.z = fmaf(e, w0.z, o0.z); o0.w = fmaf(e, w0.w, o0.w);
    o1.x = fmaf(e, w1.x, o1.x); o1.y = fmaf(e, w1.y, o1.y); o1.z = fmaf(e, w1.z, o1.z); o1.w = fmaf(e, w1.w, o1.w);
    o2.x = fmaf(e, w2.x, o2.x); o2.y = fmaf(e, w2.y, o2.y); o2.z = fmaf(e, w2.z, o2.z); o2.w = fmaf(e, w2.w, o2.w);
    o3.x = fmaf(e, w3.x, o3.x); o3.y = fmaf(e, w3.y, o3.y); o3.z = fmaf(e, w3.z, o3.z); o3.w = fmaf(e, w3.w, o3.w);
  }
  o0.x *= invl; o0.y *= invl; o0.z *= invl; o0.w *= invl;
  o1.x *= invl; o1.y *= invl; o1.z *= invl; o1.w *= invl;
  o2.x *= invl; o2.y *= invl; o2.z *= invl; o2.w *= invl;
  o3.x *= invl; o3.y *= invl; o3.z *= invl; o3.w *= invl;
  float ss = 0.f;
  ss = fmaf(o0.x, o0.x, ss); ss = fmaf(o0.y, o0.y, ss); ss = fmaf(o0.z, o0.z, ss); ss = fmaf(o0.w, o0.w, ss);
  ss = fmaf(o1.x, o1.x, ss); ss = fmaf(o1.y, o1.y, ss); ss = fmaf(o1.z, o1.z, ss); ss = fmaf(o1.w, o1.w, ss);
  ss = fmaf(o2.x, o2.x, ss); ss = fmaf(o2.y, o2.y, ss); ss = fmaf(o2.z, o2.z, ss); ss = fmaf(o2.w, o2.w, ss);
  ss = fmaf(o3.x, o3.x, ss); ss = fmaf(o3.y, o3.y, ss); ss = fmaf(o3.z, o3.z, ss); ss = fmaf(o3.w, o3.w, ss);
  pss[r][dq] = ss;
  __syncthreads();
  int orow = row0 + r;
  if (orow < rend) {
    float4* out4 = (float4*)outl;
    size_t base = (size_t)orow * 16 + dq * 4;
    out4[base + 0] = o0;
    out4[base + 1] = o1;
    out4[base + 2] = o2;
    out4[base + 3] = o3;
    if (dq == 0) {
      float t = (pss[r][0] + pss[r][1]) + (pss[r][2] + pss[r][3]);
      invn[orow] = 1.f / fmaxf(sqrtf(t), 1e-12f);
    }
  }
}

// Fused gaa+iaa: for user rows, per neighbor c compute both alphas and accumulate
// alpha*x[c]. Item rows are zero (reference segment-sums over h_idx only).
__global__ __launch_bounds__(256) void adaptive2_kernel(const int* __restrict__ off, const int* __restrict__ colarr,
                                                        const float* __restrict__ gnn, const float* __restrict__ invg,
                                                        const float* __restrict__ intl, const float* __restrict__ invi,
                                                        const float* __restrict__ x,
                                                        float* __restrict__ gaa, float* __restrict__ iaa) {
  int tid = threadIdx.x;
  int row = blockIdx.x * 16 + (tid >> 4);
  int sub = tid & 15;
  if (row >= N_NODES) return;
  float4 z = make_float4(0.f, 0.f, 0.f, 0.f);
  if (row >= NUM_USER) {
    ((float4*)gaa)[row * 16 + sub] = z;
    ((float4*)iaa)[row * 16 + sub] = z;
    return;
  }
  const float4* g4 = (const float4*)gnn;
  const float4* i4 = (const float4*)intl;
  const float4* x4 = (const float4*)x;
  float4 eg = g4[row * 16 + sub];
  float4 ei = i4[row * 16 + sub];
  float ug = invg[row], ui = invi[row];
  int s = off[row], e = off[row + 1];
  float4 ag = z, ai = z;
  for (int i = s; i < e; i++) {
    int c = colarr[i];
    float4 gt = g4[c * 16 + sub];
    float4 it = i4[c * 16 + sub];
    float dg = eg.x * gt.x + eg.y * gt.y + eg.z * gt.z + eg.w * gt.w;
    float di = ei.x * it.x + ei.y * it.y + ei.z * it.z + ei.w * it.w;
    dg += __shfl_xor(dg, 1); dg += __shfl_xor(dg, 2); dg += __shfl_xor(dg, 4); dg += __shfl_xor(dg, 8);
    di += __shfl_xor(di, 1); di += __shfl_xor(di, 2); di += __shfl_xor(di, 4); di += __shfl_xor(di, 8);
    float alg = fmaf(dg * ug * invg[c], 0.5f, 0.5f);
    float ali = fmaf(di * ui * invi[c], 0.5f, 0.5f);
    float4 xv = x4[c * 16 + sub];
    ag.x = fmaf(alg, xv.x, ag.x); ag.y = fmaf(alg, xv.y, ag.y);
    ag.z = fmaf(alg, xv.z, ag.z); ag.w = fmaf(alg, xv.w, ag.w);
    ai.x = fmaf(ali, xv.x, ai.x); ai.y = fmaf(ali, xv.y, ai.y);
    ai.z = fmaf(ali, xv.z, ai.z); ai.w = fmaf(ali, xv.w, ai.w);
  }
  ((float4*)gaa)[row * 16 + sub] = ag;
  ((float4*)iaa)[row * 16 + sub] = ai;
}

__global__ __launch_bounds__(256) void xupd_kernel(float* __restrict__ x, const float4* __restrict__ a,
                                                   const float4* __restrict__ b, const float4* __restrict__ c,
                                                   const float4* __restrict__ d) {
  int i = blockIdx.x * 256 + threadIdx.x;
  if (i >= N_NODES * 16) return;
  float4* x4 = (float4*)x;
  float4 v = x4[i], va = a[i], vb = b[i], vc = c[i], vd = d[i];
  v.x += va.x + vb.x + vc.x + vd.x;
  v.y += va.y + vb.y + vc.y + vd.y;
  v.z += va.z + vb.z + vc.z + vd.z;
  v.w += va.w + vb.w + vc.w + vd.w;
  x4[i] = v;
}

// ---------------- Host launcher ----------------

extern "C" void kernel_launch(void* const* d_in, const int* in_sizes, int n_in,
                              void* d_out, int out_size, void* d_ws, size_t ws_size,
                              hipStream_t stream) {
  const float* user_emb = (const float*)d_in[0];
  const float* item_emb = (const float*)d_in[1];
  const float* user_intent = (const float*)d_in[2];
  const float* item_intent = (const float*)d_in[3];
  const int* h_idx = (const int*)d_in[4];
  const int* t_idx = (const int*)d_in[5];
  float* out = (float*)d_out;

  char* p = (char*)d_ws;
  auto alloc = [&](size_t bytes) {
    char* r = p;
    p += (bytes + 255) & ~(size_t)255;
    return r;
  };
  int* cnt = (int*)alloc((size_t)N_NODES * 4);
  int* off = (int*)alloc((size_t)(N_NODES + 1) * 4);
  int* cursor = (int*)alloc((size_t)N_NODES * 4);
  float* dinv = (float*)alloc((size_t)N_NODES * 4);
  float* invn_g = (float*)alloc((size_t)N_NODES * 4);
  float* invn_i = (float*)alloc((size_t)N_NODES * 4);
  int* colarr = (int*)alloc((size_t)2 * N_EDGES * 4);
  float* x = (float*)alloc((size_t)N_NODES * DIM * 4);
  float* WTu = (float*)alloc((size_t)DIM * N_INTENTS * 4);
  float* WTi = (float*)alloc((size_t)DIM * N_INTENTS * 4);

  hipLaunchKernelGGL(zero_cnt_kernel, dim3((N_NODES + 255) / 256), dim3(256), 0, stream, cnt, N_NODES);
  hipLaunchKernelGGL(count_kernel, dim3((N_EDGES + 255) / 256), dim3(256), 0, stream, h_idx, t_idx, cnt);
  hipLaunchKernelGGL(scan_kernel, dim3(1), dim3(1024), 0, stream, cnt, off, cursor, dinv, N_NODES);
  hipLaunchKernelGGL(fill_kernel, dim3((N_EDGES + 255) / 256), dim3(256), 0, stream, h_idx, t_idx, cursor, colarr);
  hipLaunchKernelGGL(xinit_kernel, dim3((N_NODES * 16 + 255) / 256), dim3(256), 0, stream,
                     (float4*)x, (const float4*)user_emb, (const float4*)item_emb);
  hipLaunchKernelGGL(wtrans_kernel, dim3((DIM * N_INTENTS + 255) / 256), dim3(256), 0, stream,
                     user_intent, item_intent, WTu, WTi);

  const int UT = (NUM_USER + 63) / 64;   // 782
  const int IT = (NUM_ITEM + 63) / 64;   // 391
  const size_t SL = (size_t)N_NODES * DIM;
  for (int layer = 0; layer < 2; layer++) {
    float* gnn = out + (0 * 2 + layer) * SL;
    float* intl = out + (1 * 2 + layer) * SL;
    float* gaa = out + (2 * 2 + layer) * SL;
    float* iaa = out + (3 * 2 + layer) * SL;

    hipLaunchKernelGGL(spmm_kernel, dim3((N_NODES + 15) / 16), dim3(256), 0, stream,
                       off, colarr, dinv, x, gnn, invn_g);
    hipLaunchKernelGGL(intent_kernel, dim3(UT + IT), dim3(256), 0, stream,
                       x, WTu, WTi, intl, invn_i);
    hipLaunchKernelGGL(adaptive2_kernel, dim3((N_NODES + 15) / 16), dim3(256), 0, stream,
                       off, colarr, gnn, invn_g, intl, invn_i, x, gaa, iaa);
    if (layer == 0) {
      hipLaunchKernelGGL(xupd_kernel, dim3((N_NODES * 16 + 255) / 256), dim3(256), 0, stream,
                         x, (const float4*)gnn, (const float4*)intl, (const float4*)gaa, (const float4*)iaa);
    }
  }
}

// Round 14
// 961.057 us; speedup vs baseline: 1.2900x; 1.2900x over previous
//
#include <hip/hip_runtime.h>

#define NUM_USER 50000
#define NUM_ITEM 25000
#define N_NODES 75000
#define DIM 64
#define N_INTENTS 128
#define N_EDGES 800000

// ---------------- CSR build ----------------

__global__ __launch_bounds__(256) void zero_cnt_kernel(int* __restrict__ cnt, int n) {
  int i = blockIdx.x * 256 + threadIdx.x;
  if (i < n) cnt[i] = 0;
}

__global__ __launch_bounds__(256) void count_kernel(const int* __restrict__ h, const int* __restrict__ t,
                                                    int* __restrict__ cnt) {
  int e = blockIdx.x * 256 + threadIdx.x;
  if (e >= N_EDGES) return;
  atomicAdd(&cnt[h[e]], 1);
  atomicAdd(&cnt[t[e]], 1);
}

// Single-block exclusive scan over n=75000 counts; also emits cursor copy and dinv.
__global__ __launch_bounds__(1024) void scan_kernel(const int* __restrict__ cnt, int* __restrict__ off,
                                                    int* __restrict__ cursor, float* __restrict__ dinv, int n) {
  __shared__ int wsum[16];
  __shared__ int carry_s;
  int tid = threadIdx.x, lane = tid & 63, wid = tid >> 6;
  if (tid == 0) carry_s = 0;
  __syncthreads();
  for (int base = 0; base < n; base += 1024) {
    int idx = base + tid;
    int orig = (idx < n) ? cnt[idx] : 0;
    int v = orig;
#pragma unroll
    for (int d = 1; d < 64; d <<= 1) {
      int u = __shfl_up(v, d, 64);
      if (lane >= d) v += u;
    }
    if (lane == 63) wsum[wid] = v;
    __syncthreads();
    if (tid == 0) {
      int run = carry_s;
#pragma unroll
      for (int i = 0; i < 16; i++) { int tmp = wsum[i]; wsum[i] = run; run += tmp; }
      carry_s = run;
    }
    __syncthreads();
    if (idx < n) {
      int excl = wsum[wid] + v - orig;
      off[idx] = excl;
      cursor[idx] = excl;
      dinv[idx] = rsqrtf((float)orig + 1e-7f);
    }
    __syncthreads();
  }
  if (tid == 0) off[n] = carry_s;
}

__global__ __launch_bounds__(256) void fill_kernel(const int* __restrict__ h, const int* __restrict__ t,
                                                   int* __restrict__ cursor, int* __restrict__ colarr) {
  int e = blockIdx.x * 256 + threadIdx.x;
  if (e >= N_EDGES) return;
  int hv = h[e], tv = t[e];
  int p1 = atomicAdd(&cursor[hv], 1);
  colarr[p1] = tv;
  int p2 = atomicAdd(&cursor[tv], 1);
  colarr[p2] = hv;
}

__global__ __launch_bounds__(256) void xinit_kernel(float4* __restrict__ x, const float4* __restrict__ ue,
                                                    const float4* __restrict__ ie) {
  int i = blockIdx.x * 256 + threadIdx.x;
  if (i >= N_NODES * 16) return;
  x[i] = (i < NUM_USER * 16) ? ue[i] : ie[i - NUM_USER * 16];
}

// W [64][128] row-major  ->  WT [128][64] row-major (columns become contiguous 256B)
__global__ __launch_bounds__(256) void wtrans_kernel(const float* __restrict__ Wu, const float* __restrict__ Wi,
                                                     float* __restrict__ WTu, float* __restrict__ WTi) {
  int i = blockIdx.x * 256 + threadIdx.x;
  if (i >= DIM * N_INTENTS) return;
  int d = i >> 7, j = i & 127;
  WTu[j * 64 + d] = Wu[i];
  WTi[j * 64 + d] = Wi[i];
}

// ---------------- Per-layer kernels ----------------

// gnn[row] = dinv[row] * sum_c dinv[c] * x[c]; also invn_g[row] = 1/max(||gnn[row]||,1e-12)
__global__ __launch_bounds__(256) void spmm_kernel(const int* __restrict__ off, const int* __restrict__ colarr,
                                                   const float* __restrict__ dinv, const float* __restrict__ x,
                                                   float* __restrict__ gnn, float* __restrict__ invn) {
  int tid = threadIdx.x;
  int row = blockIdx.x * 16 + (tid >> 4);
  int sub = tid & 15;
  if (row >= N_NODES) return;
  int s = off[row], e = off[row + 1];
  const float4* x4 = (const float4*)x;
  float4 acc = make_float4(0.f, 0.f, 0.f, 0.f);
  for (int i = s; i < e; i++) {
    int c = colarr[i];
    float w = dinv[c];
    float4 xv = x4[c * 16 + sub];
    acc.x = fmaf(w, xv.x, acc.x);
    acc.y = fmaf(w, xv.y, acc.y);
    acc.z = fmaf(w, xv.z, acc.z);
    acc.w = fmaf(w, xv.w, acc.w);
  }
  float dr = dinv[row];
  acc.x *= dr; acc.y *= dr; acc.z *= dr; acc.w *= dr;
  ((float4*)gnn)[row * 16 + sub] = acc;
  float ss = acc.x * acc.x + acc.y * acc.y + acc.z * acc.z + acc.w * acc.w;
  ss += __shfl_xor(ss, 1); ss += __shfl_xor(ss, 2);
  ss += __shfl_xor(ss, 4); ss += __shfl_xor(ss, 8);
  if (sub == 0) invn[row] = 1.f / fmaxf(sqrtf(ss), 1e-12f);
}

// intl[row] = softmax(x[row] @ W) @ W^T.
// Round-12 structure (fixing vector-memory-issue bound: r4/r12 both stuck at 261us,
// VALUBusy<=13%, occupancy not the limit):
//   64 rows/block, 256 threads, lane = row in BOTH phases; wave w owns columns
//   [32w, 32w+32). W addresses are wave-uniform — readfirstlane(w) lets the
//   compiler scalarize all W reads to s_load (SMEM pipe, SGPR-resident), removing
//   ~4096 wave64 vector loads per block from the TA pipe. Scores/exp stay in
//   registers (no Pe buffer). Cross-wave o-reduction: padded Ol[64][68] in LDS,
//   4 barrier-sequenced add rounds. Fallback if scalarization fails: emitted
//   load count equals the round-5 version (no regression).
__global__ __launch_bounds__(256) void intent_kernel(const float* __restrict__ x,
                                                     const float* __restrict__ WTu,
                                                     const float* __restrict__ WTi,
                                                     float* __restrict__ outl, float* __restrict__ invn) {
  __shared__ float Ol[64 * 68];   // 17.4 KB, +68 stride keeps 16B align & spreads banks
  __shared__ float pm[4][64];
  __shared__ float pl[4][64];
  __shared__ float pss[64][4];
  const int UT = (NUM_USER + 63) / 64;  // 782
  int b = blockIdx.x;
  const float* WT;
  int row0, rend;
  if (b < UT) { WT = WTu; row0 = b * 64; rend = NUM_USER; }
  else        { WT = WTi; row0 = NUM_USER + (b - UT) * 64; rend = N_NODES; }
  int tid = threadIdx.x, w = tid >> 6, lane = tid & 63;
  int ws = __builtin_amdgcn_readfirstlane(w);   // provably wave-uniform wave id
  const float4* WT4 = (const float4*)WT;
  const float4* x4 = (const float4*)x;

  int row = row0 + lane;
  bool act = row < rend;
  float4 zf4 = make_float4(0.f, 0.f, 0.f, 0.f);
  float4 xr[16];
#pragma unroll
  for (int q = 0; q < 16; q++) xr[q] = act ? x4[(size_t)row * 16 + q] : zf4;

  // ---- phase 1: scores for this wave's 32 columns (W reads uniform -> s_load) ----
  int j0 = ws * 32;
  float s[32];
#pragma unroll
  for (int jj = 0; jj < 32; jj++) {
    const float4* wj = WT4 + (size_t)(j0 + jj) * 16;   // uniform address
    float s0 = 0.f, s1 = 0.f, s2 = 0.f, s3 = 0.f;
#pragma unroll
    for (int q = 0; q < 16; q += 4) {
      float4 a0 = xr[q],     w0 = wj[q];
      float4 a1 = xr[q + 1], w1 = wj[q + 1];
      float4 a2 = xr[q + 2], w2 = wj[q + 2];
      float4 a3 = xr[q + 3], w3 = wj[q + 3];
      s0 = fmaf(a0.x, w0.x, s0); s0 = fmaf(a0.y, w0.y, s0); s0 = fmaf(a0.z, w0.z, s0); s0 = fmaf(a0.w, w0.w, s0);
      s1 = fmaf(a1.x, w1.x, s1); s1 = fmaf(a1.y, w1.y, s1); s1 = fmaf(a1.z, w1.z, s1); s1 = fmaf(a1.w, w1.w, s1);
      s2 = fmaf(a2.x, w2.x, s2); s2 = fmaf(a2.y, w2.y, s2); s2 = fmaf(a2.z, w2.z, s2); s2 = fmaf(a2.w, w2.w, s2);
      s3 = fmaf(a3.x, w3.x, s3); s3 = fmaf(a3.y, w3.y, s3); s3 = fmaf(a3.z, w3.z, s3); s3 = fmaf(a3.w, w3.w, s3);
    }
    s[jj] = (s0 + s1) + (s2 + s3);
  }
  float pmax = s[0];
#pragma unroll
  for (int jj = 1; jj < 32; jj++) pmax = fmaxf(pmax, s[jj]);
  pm[w][lane] = pmax;
  __syncthreads();
  float m = fmaxf(fmaxf(pm[0][lane], pm[1][lane]), fmaxf(pm[2][lane], pm[3][lane]));
  float e[32];
  float psum = 0.f;
#pragma unroll
  for (int jj = 0; jj < 32; jj++) { e[jj] = expf(s[jj] - m); psum += e[jj]; }
  pl[w][lane] = psum;

  // ---- phase 2: o[row][0..64) partial over this wave's 32 columns (W uniform) ----
  float4 o[16];
#pragma unroll
  for (int q = 0; q < 16; q++) o[q] = zf4;
#pragma unroll
  for (int jj = 0; jj < 32; jj++) {
    const float4* wj = WT4 + (size_t)(j0 + jj) * 16;   // uniform address
    float ee = e[jj];
#pragma unroll
    for (int q = 0; q < 16; q++) {
      float4 wq = wj[q];
      o[q].x = fmaf(ee, wq.x, o[q].x);
      o[q].y = fmaf(ee, wq.y, o[q].y);
      o[q].z = fmaf(ee, wq.z, o[q].z);
      o[q].w = fmaf(ee, wq.w, o[q].w);
    }
  }

  // ---- cross-wave reduction: 4 barrier-sequenced rounds into Ol ----
  float4* Orow = (float4*)&Ol[lane * 68];   // 272B row stride, 16B aligned
  for (int t = 0; t < 4; t++) {
    if (w == t) {
      if (t == 0) {
#pragma unroll
        for (int q = 0; q < 16; q++) Orow[q] = o[q];
      } else {
#pragma unroll
        for (int q = 0; q < 16; q++) {
          float4 v = Orow[q];
          v.x += o[q].x; v.y += o[q].y; v.z += o[q].z; v.w += o[q].w;
          Orow[q] = v;
        }
      }
    }
    __syncthreads();
  }

  // ---- epilogue: scale by 1/l, store coalesced, row norm ----
  int r = tid >> 2, dq = tid & 3;
  float lsum = (pl[0][r] + pl[1][r]) + (pl[2][r] + pl[3][r]);
  float invl = 1.f / lsum;  // >=1: max column contributes e=1
  const float4* Or = (const float4*)&Ol[r * 68];
  float4 v0 = Or[dq * 4 + 0], v1 = Or[dq * 4 + 1], v2 = Or[dq * 4 + 2], v3 = Or[dq * 4 + 3];
  v0.x *= invl; v0.y *= invl; v0.z *= invl; v0.w *= invl;
  v1.x *= invl; v1.y *= invl; v1.z *= invl; v1.w *= invl;
  v2.x *= invl; v2.y *= invl; v2.z *= invl; v2.w *= invl;
  v3.x *= invl; v3.y *= invl; v3.z *= invl; v3.w *= invl;
  float ss = 0.f;
  ss = fmaf(v0.x, v0.x, ss); ss = fmaf(v0.y, v0.y, ss); ss = fmaf(v0.z, v0.z, ss); ss = fmaf(v0.w, v0.w, ss);
  ss = fmaf(v1.x, v1.x, ss); ss = fmaf(v1.y, v1.y, ss); ss = fmaf(v1.z, v1.z, ss); ss = fmaf(v1.w, v1.w, ss);
  ss = fmaf(v2.x, v2.x, ss); ss = fmaf(v2.y, v2.y, ss); ss = fmaf(v2.z, v2.z, ss); ss = fmaf(v2.w, v2.w, ss);
  ss = fmaf(v3.x, v3.x, ss); ss = fmaf(v3.y, v3.y, ss); ss = fmaf(v3.z, v3.z, ss); ss = fmaf(v3.w, v3.w, ss);
  pss[r][dq] = ss;
  __syncthreads();
  int orow = row0 + r;
  if (orow < rend) {
    float4* out4 = (float4*)outl;
    size_t base = (size_t)orow * 16 + dq * 4;
    out4[base + 0] = v0;
    out4[base + 1] = v1;
    out4[base + 2] = v2;
    out4[base + 3] = v3;
    if (dq == 0) {
      float tt = (pss[r][0] + pss[r][1]) + (pss[r][2] + pss[r][3]);
      invn[orow] = 1.f / fmaxf(sqrtf(tt), 1e-12f);
    }
  }
}

// Fused gaa+iaa: for user rows, per neighbor c compute both alphas and accumulate
// alpha*x[c]. Item rows are zero (reference segment-sums over h_idx only).
__global__ __launch_bounds__(256) void adaptive2_kernel(const int* __restrict__ off, const int* __restrict__ colarr,
                                                        const float* __restrict__ gnn, const float* __restrict__ invg,
                                                        const float* __restrict__ intl, const float* __restrict__ invi,
                                                        const float* __restrict__ x,
                                                        float* __restrict__ gaa, float* __restrict__ iaa) {
  int tid = threadIdx.x;
  int row = blockIdx.x * 16 + (tid >> 4);
  int sub = tid & 15;
  if (row >= N_NODES) return;
  float4 z = make_float4(0.f, 0.f, 0.f, 0.f);
  if (row >= NUM_USER) {
    ((float4*)gaa)[row * 16 + sub] = z;
    ((float4*)iaa)[row * 16 + sub] = z;
    return;
  }
  const float4* g4 = (const float4*)gnn;
  const float4* i4 = (const float4*)intl;
  const float4* x4 = (const float4*)x;
  float4 eg = g4[row * 16 + sub];
  float4 ei = i4[row * 16 + sub];
  float ug = invg[row], ui = invi[row];
  int s = off[row], e = off[row + 1];
  float4 ag = z, ai = z;
  for (int i = s; i < e; i++) {
    int c = colarr[i];
    float4 gt = g4[c * 16 + sub];
    float4 it = i4[c * 16 + sub];
    float dg = eg.x * gt.x + eg.y * gt.y + eg.z * gt.z + eg.w * gt.w;
    float di = ei.x * it.x + ei.y * it.y + ei.z * it.z + ei.w * it.w;
    dg += __shfl_xor(dg, 1); dg += __shfl_xor(dg, 2); dg += __shfl_xor(dg, 4); dg += __shfl_xor(dg, 8);
    di += __shfl_xor(di, 1); di += __shfl_xor(di, 2); di += __shfl_xor(di, 4); di += __shfl_xor(di, 8);
    float alg = fmaf(dg * ug * invg[c], 0.5f, 0.5f);
    float ali = fmaf(di * ui * invi[c], 0.5f, 0.5f);
    float4 xv = x4[c * 16 + sub];
    ag.x = fmaf(alg, xv.x, ag.x); ag.y = fmaf(alg, xv.y, ag.y);
    ag.z = fmaf(alg, xv.z, ag.z); ag.w = fmaf(alg, xv.w, ag.w);
    ai.x = fmaf(ali, xv.x, ai.x); ai.y = fmaf(ali, xv.y, ai.y);
    ai.z = fmaf(ali, xv.z, ai.z); ai.w = fmaf(ali, xv.w, ai.w);
  }
  ((float4*)gaa)[row * 16 + sub] = ag;
  ((float4*)iaa)[row * 16 + sub] = ai;
}

__global__ __launch_bounds__(256) void xupd_kernel(float* __restrict__ x, const float4* __restrict__ a,
                                                   const float4* __restrict__ b, const float4* __restrict__ c,
                                                   const float4* __restrict__ d) {
  int i = blockIdx.x * 256 + threadIdx.x;
  if (i >= N_NODES * 16) return;
  float4* x4 = (float4*)x;
  float4 v = x4[i], va = a[i], vb = b[i], vc = c[i], vd = d[i];
  v.x += va.x + vb.x + vc.x + vd.x;
  v.y += va.y + vb.y + vc.y + vd.y;
  v.z += va.z + vb.z + vc.z + vd.z;
  v.w += va.w + vb.w + vc.w + vd.w;
  x4[i] = v;
}

// ---------------- Host launcher ----------------

extern "C" void kernel_launch(void* const* d_in, const int* in_sizes, int n_in,
                              void* d_out, int out_size, void* d_ws, size_t ws_size,
                              hipStream_t stream) {
  const float* user_emb = (const float*)d_in[0];
  const float* item_emb = (const float*)d_in[1];
  const float* user_intent = (const float*)d_in[2];
  const float* item_intent = (const float*)d_in[3];
  const int* h_idx = (const int*)d_in[4];
  const int* t_idx = (const int*)d_in[5];
  float* out = (float*)d_out;

  char* p = (char*)d_ws;
  auto alloc = [&](size_t bytes) {
    char* r = p;
    p += (bytes + 255) & ~(size_t)255;
    return r;
  };
  int* cnt = (int*)alloc((size_t)N_NODES * 4);
  int* off = (int*)alloc((size_t)(N_NODES + 1) * 4);
  int* cursor = (int*)alloc((size_t)N_NODES * 4);
  float* dinv = (float*)alloc((size_t)N_NODES * 4);
  float* invn_g = (float*)alloc((size_t)N_NODES * 4);
  float* invn_i = (float*)alloc((size_t)N_NODES * 4);
  int* colarr = (int*)alloc((size_t)2 * N_EDGES * 4);
  float* x = (float*)alloc((size_t)N_NODES * DIM * 4);
  float* WTu = (float*)alloc((size_t)DIM * N_INTENTS * 4);
  float* WTi = (float*)alloc((size_t)DIM * N_INTENTS * 4);

  hipLaunchKernelGGL(zero_cnt_kernel, dim3((N_NODES + 255) / 256), dim3(256), 0, stream, cnt, N_NODES);
  hipLaunchKernelGGL(count_kernel, dim3((N_EDGES + 255) / 256), dim3(256), 0, stream, h_idx, t_idx, cnt);
  hipLaunchKernelGGL(scan_kernel, dim3(1), dim3(1024), 0, stream, cnt, off, cursor, dinv, N_NODES);
  hipLaunchKernelGGL(fill_kernel, dim3((N_EDGES + 255) / 256), dim3(256), 0, stream, h_idx, t_idx, cursor, colarr);
  hipLaunchKernelGGL(xinit_kernel, dim3((N_NODES * 16 + 255) / 256), dim3(256), 0, stream,
                     (float4*)x, (const float4*)user_emb, (const float4*)item_emb);
  hipLaunchKernelGGL(wtrans_kernel, dim3((DIM * N_INTENTS + 255) / 256), dim3(256), 0, stream,
                     user_intent, item_intent, WTu, WTi);

  const int UT = (NUM_USER + 63) / 64;   // 782
  const int IT = (NUM_ITEM + 63) / 64;   // 391
  const size_t SL = (size_t)N_NODES * DIM;
  for (int layer = 0; layer < 2; layer++) {
    float* gnn = out + (0 * 2 + layer) * SL;
    float* intl = out + (1 * 2 + layer) * SL;
    float* gaa = out + (2 * 2 + layer) * SL;
    float* iaa = out + (3 * 2 + layer) * SL;

    hipLaunchKernelGGL(spmm_kernel, dim3((N_NODES + 15) / 16), dim3(256), 0, stream,
                       off, colarr, dinv, x, gnn, invn_g);
    hipLaunchKernelGGL(intent_kernel, dim3(UT + IT), dim3(256), 0, stream,
                       x, WTu, WTi, intl, invn_i);
    hipLaunchKernelGGL(adaptive2_kernel, dim3((N_NODES + 15) / 16), dim3(256), 0, stream,
                       off, colarr, gnn, invn_g, intl, invn_i, x, gaa, iaa);
    if (layer == 0) {
      hipLaunchKernelGGL(xupd_kernel, dim3((N_NODES * 16 + 255) / 256), dim3(256), 0, stream,
                         x, (const float4*)gnn, (const float4*)intl, (const float4*)gaa, (const float4*)iaa);
    }
  }
}